// Round 8
// baseline (211.727 us; speedup 1.0000x reference)
//
#include <hip/hip_runtime.h>

// Problem constants (from reference)
constexpr int B   = 4;
constexpr int CF  = 3;    // feat channels
constexpr int CM  = 21;   // mask channels
constexpr int H   = 128;
constexpr int W   = 128;
constexpr int KS  = 7;
constexpr int PAD = 3;
constexpr int CENTER = (KS * KS) / 2;  // 24
constexpr int NNB = KS * KS - 1;       // 48 neighbors
constexpr int NUM_ITER = 10;

constexpr int TILE  = 16;
constexpr int TH    = TILE + 2 * PAD;  // 22
constexpr int TS    = 24;              // LDS row stride (even -> b64-aligned pairs; 24*r+2tx spreads banks uniformly)
constexpr int PLANE = TH * TS;         // 528
constexpr int HW    = H * W;
constexpr int TPB   = 768;             // (8,16,6)

// ---------------------------------------------------------------------------
// Kernel 1: per-pixel 48-way softmax affinity from feats (validated).
// aff layout: aff[((b*48 + n)*H + h)*W + w]  (plane-major, coalesced in w)
// ---------------------------------------------------------------------------
__global__ __launch_bounds__(256) void aff_kernel(const float* __restrict__ feats,
                                                  float* __restrict__ aff) {
    __shared__ float tile[CF][TH][TS];
    const int tx = threadIdx.x, ty = threadIdx.y;
    const int bx = blockIdx.x * TILE, by = blockIdx.y * TILE;
    const int b  = blockIdx.z;
    const int tid = ty * TILE + tx;

    for (int c = 0; c < CF; ++c) {
        const float* src = feats + (size_t)(b * CF + c) * HW;
        for (int idx = tid; idx < TH * TH; idx += 256) {
            const int r  = idx / TH, cc = idx - r * TH;
            const int gh = min(max(by + r  - PAD, 0), H - 1);
            const int gw = min(max(bx + cc - PAD, 0), W - 1);
            tile[c][r][cc] = src[gh * W + gw];
        }
    }
    __syncthreads();

    float q[CF], inv[CF];
    #pragma unroll
    for (int c = 0; c < CF; ++c) {
        const float* tp = &tile[c][ty][tx];
        q[c] = tp[PAD * TS + PAD];
        float s = 0.f, s2 = 0.f;
        #pragma unroll
        for (int i = 0; i < KS; ++i)
            #pragma unroll
            for (int j = 0; j < KS; ++j) {
                if (i == PAD && j == PAD) continue;
                const float v = tp[i * TS + j];
                s += v; s2 += v * v;
            }
        const float mean = s * (1.0f / NNB);
        const float var  = fmaxf(s2 - (float)NNB * mean * mean, 0.f) * (1.0f / (NNB - 1));
        inv[c] = 1.0f / (1e-8f + 0.1f * sqrtf(var));
    }

    float a[NNB];
    float mx = -1e30f;
    #pragma unroll
    for (int i = 0; i < KS; ++i)
        #pragma unroll
        for (int j = 0; j < KS; ++j) {
            const int nn = i * KS + j;
            if (nn == CENTER) continue;
            const int n = (nn < CENTER) ? nn : nn - 1;
            float t = 0.f;
            #pragma unroll
            for (int c = 0; c < CF; ++c)
                t += fabsf(tile[c][ty + i][tx + j] - q[c]) * inv[c];
            a[n] = -t * (1.0f / CF);
            mx = fmaxf(mx, a[n]);
        }
    float ssum = 0.f;
    #pragma unroll
    for (int n = 0; n < NNB; ++n) { a[n] = __expf(a[n] - mx); ssum += a[n]; }
    const float rs = 1.0f / ssum;

    const int h = by + ty, w = bx + tx;
    #pragma unroll
    for (int n = 0; n < NNB; ++n)
        aff[(((size_t)b * NNB + n) * H + h) * W + w] = a[n] * rs;
}

// ---------------------------------------------------------------------------
// Kernel 2: one propagation iteration. Block (8,16,6)=768 thr, grid 256.
// Each thread owns a HORIZONTAL PIXEL PAIR: window rows read as 4 aligned
// ds_read_b64 (28 b64/channel vs 96 b32). aff = 48 float2 registers loaded
// directly from global (read once; no aff LDS). z-slice owns {4,4,4,3,3,3} ch.
// ---------------------------------------------------------------------------
__global__ __launch_bounds__(TPB, 3) void iter_kernel(const float* __restrict__ mi,
                                                      const float* __restrict__ aff,
                                                      float* __restrict__ mo) {
    __shared__ float mt[CM][TH][TS];     // 44.4 KB (mask halo tiles only)
    float* tf = &mt[0][0][0];

    const int tx = threadIdx.x;          // 0..7  (pixel-pair column)
    const int ty = threadIdx.y;          // 0..15
    const int tz = threadIdx.z;          // 0..5  (channel slice)
    const int bx = blockIdx.x * TILE, by = blockIdx.y * TILE;
    const int b  = blockIdx.z;
    const int tid = (tz * TILE + ty) * 8 + tx;
    const int h  = by + ty;
    const int w0 = bx + 2 * tx;

    const int c0  = (tz < 3) ? tz * 4 : 12 + (tz - 3) * 3;
    const int cnt = (tz < 3) ? 4 : 3;

    // ---- aff -> 48 float2 registers (8B coalesced, L3-resident, read once)
    float2 a2[NNB];
    {
        const float2* ab = (const float2*)(aff + (size_t)b * NNB * HW + h * W + w0);
        #pragma unroll
        for (int n = 0; n < NNB; ++n)
            a2[n] = ab[(size_t)n * (HW / 2)];
    }

    // ---- stage all 21 channel halo tiles (484 active threads, 21 planes each)
    if (tid < TH * TH) {
        const int r  = tid / TH, q = tid - r * TH;
        const int gh = min(max(by + r - PAD, 0), H - 1);
        const int gw = min(max(bx + q - PAD, 0), W - 1);
        const int go = gh * W + gw, lo = r * TS + q;
        const float* src = mi + (size_t)b * CM * HW;
        #pragma unroll
        for (int c = 0; c < CM; ++c)
            tf[c * PLANE + lo] = src[c * HW + go];
    }
    __syncthreads();

    // ---- per channel: 7 rows x 4 ds_read_b64, 96 FMAs for the pixel pair
    float* dp = mo + (size_t)b * CM * HW + h * W + w0;
    #pragma unroll
    for (int k = 0; k < 4; ++k) {
        if (k >= cnt) break;               // wave-uniform (slice-uniform)
        const int c = c0 + k;
        const float* tp = tf + c * PLANE + ty * TS + 2 * tx;
        float s0 = 0.f, s1 = 0.f;
        #pragma unroll
        for (int i = 0; i < KS; ++i) {
            const float2 r0 = *(const float2*)(tp + i * TS);
            const float2 r1 = *(const float2*)(tp + i * TS + 2);
            const float2 r2 = *(const float2*)(tp + i * TS + 4);
            const float2 r3 = *(const float2*)(tp + i * TS + 6);
            const float rr[8] = { r0.x, r0.y, r1.x, r1.y, r2.x, r2.y, r3.x, r3.y };
            #pragma unroll
            for (int j = 0; j < KS; ++j) {
                const int nn = i * KS + j;
                if (nn == CENTER) continue;          // center skipped for BOTH pixels
                const int n = (nn < CENTER) ? nn : nn - 1;
                s0 += a2[n].x * rr[j];               // pixel p   : window col j
                s1 += a2[n].y * rr[j + 1];           // pixel p+1 : window col j+1
            }
        }
        *(float2*)(dp + (size_t)c * HW) = make_float2(s0, s1);
    }
}

// ---------------------------------------------------------------------------
extern "C" void kernel_launch(void* const* d_in, const int* in_sizes, int n_in,
                              void* d_out, int out_size, void* d_ws, size_t ws_size,
                              hipStream_t stream) {
    const float* feats = (const float*)d_in[0];
    const float* mask  = (const float*)d_in[1];
    float* out = (float*)d_out;

    float* aff  = (float*)d_ws;                               // 12.58 MB
    float* buf0 = aff  + (size_t)B * NNB * HW;                // 5.5 MB
    float* buf1 = buf0 + (size_t)B * CM  * HW;                // 5.5 MB

    dim3 grid(W / TILE, H / TILE, B);
    aff_kernel<<<grid, dim3(TILE, TILE), 0, stream>>>(feats, aff);

    const float* srcp = mask;
    for (int t = 1; t <= NUM_ITER; ++t) {
        float* dst = (t == NUM_ITER) ? out : ((t & 1) ? buf0 : buf1);
        iter_kernel<<<grid, dim3(8, TILE, 6), 0, stream>>>(srcp, aff, dst);
        srcp = dst;
    }
}